// Round 1
// baseline (150.502 us; speedup 1.0000x reference)
//
#include <hip/hip_runtime.h>
#include <cstdint>

#define NN 1024
#define BB 32
#define LL 128
#define DE 16
#define HH 4
#define K1 4
#define BD 512
#define NS 524288   // NN*BD elements per head slab

using bf16x8 = __attribute__((ext_vector_type(8))) short;
using f32x4  = __attribute__((ext_vector_type(4))) float;
using u16x4  = __attribute__((ext_vector_type(4))) unsigned short;

__device__ inline unsigned short f2bf(float f) {
    unsigned u = __builtin_bit_cast(unsigned, f);
    u += 0x7FFFu + ((u >> 16) & 1u);          // round-to-nearest-even
    return (unsigned short)(u >> 16);
}
__device__ inline float bf2f(unsigned short u) {
    return __builtin_bit_cast(float, (unsigned)u << 16);
}

// async global->LDS, 16B per lane; LDS dest is wave-uniform base + lane*16
typedef const __attribute__((address_space(1))) void gas_void;
typedef __attribute__((address_space(3))) void las_void;
#define GLD16(gsrc, ldst) \
    __builtin_amdgcn_global_load_lds((gas_void*)(gsrc), (las_void*)(ldst), 16, 0, 0)

struct LogitsSmem {
    float ejs[64][17];
    float eis[64][17];
    float kjs[64][64];
    float qis[4][64][17];
    float part[4][5][64];
    float wq[1024];
    float wk[1024];
};
struct XtSmem { float xs[64][128]; };

// ================================================================ PHASE 1
// logits (256) | xt_cast (512) | wtt_cast (16) | zero-out (16) = 800 blocks.
__global__ __launch_bounds__(256) void phase1(
    const float* __restrict__ psi_emb, const float* __restrict__ psi_p,
    const float* __restrict__ W_q, const float* __restrict__ W_k,
    const float* __restrict__ x, const float* __restrict__ F_w,
    short* __restrict__ bnt, short* __restrict__ ant, float* __restrict__ partials,
    short* __restrict__ xt, short* __restrict__ wtt, float* __restrict__ out)
{
    __shared__ __align__(16) char smem_raw[sizeof(LogitsSmem)];
    const int bid = blockIdx.x;
    const int tid = threadIdx.x;

    if (bid < 256) {
        // ---------------- logits role (inline Q/K projection)
        LogitsSmem& S = *(LogitsSmem*)smem_raw;
        const int jb = bid & 15, ib = bid >> 4;
        const int i0 = ib * 64, j0 = jb * 64;
        {
            const int row = tid >> 2, dq = (tid & 3) * 4;
            const float4 vj = *(const float4*)(psi_emb + (j0 + row) * DE + dq);
            S.ejs[row][dq] = vj.x; S.ejs[row][dq + 1] = vj.y;
            S.ejs[row][dq + 2] = vj.z; S.ejs[row][dq + 3] = vj.w;
            const float4 vi = *(const float4*)(psi_emb + (i0 + row) * DE + dq);
            S.eis[row][dq] = vi.x; S.eis[row][dq + 1] = vi.y;
            S.eis[row][dq + 2] = vi.z; S.eis[row][dq + 3] = vi.w;
            *(float4*)&S.wq[tid * 4] = *(const float4*)(W_q + tid * 4);
            *(float4*)&S.wk[tid * 4] = *(const float4*)(W_k + tid * 4);
        }
        __syncthreads();
#pragma unroll
        for (int rep = 0; rep < 16; rep++) {
            const int idx = rep * 256 + tid;
            const int row = idx >> 6, hm = idx & 63;
            float qv = 0.f, kv = 0.f;
#pragma unroll
            for (int d = 0; d < DE; d++) {
                qv += S.eis[row][d] * S.wq[d * 64 + hm];
                kv += S.ejs[row][d] * S.wk[d * 64 + hm];
            }
            S.qis[hm >> 4][row][hm & 15] = qv;
            S.kjs[row][hm] = kv;
        }
        __syncthreads();

        const int i = tid & 63, jg = tid >> 6;
        const float psi = psi_p[0];
        float er[DE];
#pragma unroll
        for (int d = 0; d < DE; d++) er[d] = S.eis[i][d];

        float sb = 0.f, sa[HH] = {0.f, 0.f, 0.f, 0.f};
#pragma unroll
        for (int g = 0; g < 2; g++) {
            unsigned short bw[8];
#pragma unroll
            for (int r = 0; r < 8; r++) {
                const int j = jg * 16 + g * 8 + r;
                float d2 = 0.f;
#pragma unroll
                for (int d = 0; d < DE; d++) { const float t = er[d] - S.ejs[j][d]; d2 += t * t; }
                const float bn = __expf(__expf(-psi * d2));
                sb += bn;
                bw[r] = f2bf(bn);
            }
            uint4 pk;
            pk.x = bw[0] | ((unsigned)bw[1] << 16);
            pk.y = bw[2] | ((unsigned)bw[3] << 16);
            pk.z = bw[4] | ((unsigned)bw[5] << 16);
            pk.w = bw[6] | ((unsigned)bw[7] << 16);
            const size_t toff = (size_t)((j0 + jg * 16 + g * 8) >> 3) * 8192 + (size_t)(i0 + i) * 8;
            *(uint4*)(bnt + toff) = pk;
        }
#pragma unroll
        for (int h = 0; h < HH; h++) {
            float qr[DE];
#pragma unroll
            for (int m = 0; m < DE; m++) qr[m] = S.qis[h][i][m];
#pragma unroll
            for (int g = 0; g < 2; g++) {
                unsigned short aw[8];
#pragma unroll
                for (int r = 0; r < 8; r++) {
                    const int j = jg * 16 + g * 8 + r;
                    float dot = 0.f;
#pragma unroll
                    for (int m = 0; m < DE; m++) dot += qr[m] * S.kjs[j][h * DE + m];
                    const float an = __expf(dot * 0.25f);
                    sa[h] += an;
                    aw[r] = f2bf(an);
                }
                uint4 pk;
                pk.x = aw[0] | ((unsigned)aw[1] << 16);
                pk.y = aw[2] | ((unsigned)aw[3] << 16);
                pk.z = aw[4] | ((unsigned)aw[5] << 16);
                pk.w = aw[6] | ((unsigned)aw[7] << 16);
                const size_t toff = (size_t)((j0 + jg * 16 + g * 8) >> 3) * 8192 + (size_t)(i0 + i) * 8;
                *(uint4*)(ant + (size_t)h * 1048576 + toff) = pk;
            }
        }
        S.part[jg][0][i] = sb;
#pragma unroll
        for (int h = 0; h < HH; h++) S.part[jg][1 + h][i] = sa[h];
        __syncthreads();
        if (tid < 64) {
#pragma unroll
            for (int s = 0; s < 5; s++) {
                const float v = S.part[0][s][tid] + S.part[1][s][tid] +
                                S.part[2][s][tid] + S.part[3][s][tid];
                partials[(size_t)jb * 5120 + (size_t)s * 1024 + i0 + tid] = v;
            }
        }
    } else if (bid < 768) {
        // ---------------- xt_cast role
        XtSmem& X = *(XtSmem*)smem_raw;
        const int idx = bid - 256;
        const int m0 = (idx & 15) * 64;
        const int b  = idx >> 4;
        for (int i = tid; i < 2048; i += 256) {
            const int row = i >> 5, lq = i & 31;
            *(float4*)&X.xs[row][lq * 4] =
                *(const float4*)(x + ((size_t)(b * NN + m0 + row)) * LL + lq * 4);
        }
        __syncthreads();
        for (int j = tid; j < 1024; j += 256) {
            const int m = j & 63, lc = j >> 6;
            const float* s = &X.xs[m][lc * 8];
            uint4 pk;
            pk.x = f2bf(s[0]) | ((unsigned)f2bf(s[1]) << 16);
            pk.y = f2bf(s[2]) | ((unsigned)f2bf(s[3]) << 16);
            pk.z = f2bf(s[4]) | ((unsigned)f2bf(s[5]) << 16);
            pk.w = f2bf(s[6]) | ((unsigned)f2bf(s[7]) << 16);
            *(uint4*)(xt + (size_t)b * 131072 + (size_t)lc * 8192 + (size_t)(m0 + m) * 8) = pk;
        }
    } else if (bid < 784) {
        // ---------------- wtt_cast role
        const int j = (bid - 768) * 256 + tid;
        const int lc = j >> 8, c = j & 255;
        const int h = c >> 6, k = (c >> 4) & 3, d = c & 15;
        const float* s = F_w + (size_t)((h * DE + d) * K1 + k) * LL + lc * 8;
        uint4 pk;
        pk.x = f2bf(s[0]) | ((unsigned)f2bf(s[1]) << 16);
        pk.y = f2bf(s[2]) | ((unsigned)f2bf(s[3]) << 16);
        pk.z = f2bf(s[4]) | ((unsigned)f2bf(s[5]) << 16);
        pk.w = f2bf(s[6]) | ((unsigned)f2bf(s[7]) << 16);
        *(uint4*)(wtt + (size_t)lc * 2048 + (size_t)c * 8) = pk;
    } else {
        // ---------------- zero-out role (out is poisoned 0xAA each launch)
        const int idx = (bid - 784) * 256 + tid;       // 4096 threads, 8 floats each
        const float4 z = {0.f, 0.f, 0.f, 0.f};
        *(float4*)(out + (size_t)idx * 8) = z;
        *(float4*)(out + (size_t)idx * 8 + 4) = z;
    }
}

// ================================================================ PHASE 2
// g_mfma (1024 blocks, all-bf16 tiled Gt output) + blend (256 blocks).
__global__ __launch_bounds__(256) void phase2(
    const short* __restrict__ xt, const short* __restrict__ wtt,
    short* __restrict__ Gt,
    const short* __restrict__ bnt, const short* __restrict__ ant,
    const float* __restrict__ partials, const float* __restrict__ alpha_p,
    short* __restrict__ At)
{
    const int bid = blockIdx.x;
    const int tid = threadIdx.x;
    __shared__ float sums_l[5][64];

    if (bid < 1024) {
        // ---------------- g_mfma role
        const int cb = bid & 3;
        const int m0 = ((bid >> 2) & 15) * 64;
        const int bp = bid >> 6;
        const int wave = tid >> 6, lane = tid & 63;
        const int b  = bp * 2 + (wave >> 1);
        const int wc = wave & 1;
        const int q = lane >> 4, m16 = lane & 15;
        const short* xb = xt + (size_t)b * 131072;

        f32x4 acc[4][2];
#pragma unroll
        for (int mi = 0; mi < 4; mi++)
#pragma unroll
            for (int ni = 0; ni < 2; ni++) acc[mi][ni] = (f32x4){0.f, 0.f, 0.f, 0.f};

#pragma unroll
        for (int ks = 0; ks < 4; ks++) {
            const int kc = ks * 4 + q;
            bf16x8 a[4], bb[2];
#pragma unroll
            for (int mi = 0; mi < 4; mi++)
                a[mi] = *(const bf16x8*)(xb + (size_t)kc * 8192 + (size_t)(m0 + mi * 16 + m16) * 8);
#pragma unroll
            for (int ni = 0; ni < 2; ni++)
                bb[ni] = *(const bf16x8*)(wtt + (size_t)kc * 2048 +
                                          (size_t)(cb * 64 + wc * 32 + ni * 16 + m16) * 8);
#pragma unroll
            for (int mi = 0; mi < 4; mi++)
#pragma unroll
                for (int ni = 0; ni < 2; ni++)
                    acc[mi][ni] = __builtin_amdgcn_mfma_f32_16x16x32_bf16(a[mi], bb[ni], acc[mi][ni], 0, 0, 0);
        }

        // bf16 tiled stores only (full-line coalesced); slab = kk*4+hh
#pragma unroll
        for (int ni = 0; ni < 2; ni++) {
            const int cc = cb * 64 + wc * 32 + ni * 16 + m16;
            const int kk = (cc >> 4) & 3, hh = cc >> 6;
            const int col512 = b * 16 + (cc & 15);
            short* gdst = Gt + (size_t)(kk * 4 + hh) * 524288;
#pragma unroll
            for (int mi = 0; mi < 4; mi++) {
                const int row0 = m0 + mi * 16 + q * 4;
                ushort4 pk;
                pk.x = f2bf(acc[mi][ni][0]); pk.y = f2bf(acc[mi][ni][1]);
                pk.z = f2bf(acc[mi][ni][2]); pk.w = f2bf(acc[mi][ni][3]);
                *(ushort4*)(gdst + ((size_t)(row0 >> 3) * 512 + col512) * 8 + (row0 & 7)) = pk;
            }
        }
    } else {
        // ---------------- blend role
        const int idx = bid - 1024;
        const int jb = idx & 15, ib = idx >> 4;
        const int i0 = ib * 64, j0 = jb * 64;
        const int lane = tid & 63, w = tid >> 6;
        {
            float acc = 0.f;
#pragma unroll
            for (int jb2 = 0; jb2 < 16; jb2++)
                acc += partials[(size_t)jb2 * 5120 + (size_t)w * 1024 + i0 + lane];
            sums_l[w][lane] = acc;
            if (w == 0) {
                float a4 = 0.f;
#pragma unroll
                for (int jb2 = 0; jb2 < 16; jb2++)
                    a4 += partials[(size_t)jb2 * 5120 + 4 * 1024 + i0 + lane];
                sums_l[4][lane] = a4;
            }
        }
        __syncthreads();
        const int i = lane, jg = w;
        const float alpha = 1.f / (1.f + __expf(-alpha_p[0]));
        const float ibs = alpha / sums_l[0][i];
        float ias[HH];
#pragma unroll
        for (int h = 0; h < HH; h++) ias[h] = (1.f - alpha) / sums_l[1 + h][i];

#pragma unroll
        for (int g = 0; g < 2; g++) {
            const size_t toff = (size_t)((j0 + jg * 16 + g * 8) >> 3) * 8192 + (size_t)(i0 + i) * 8;
            const uint4 bp = *(const uint4*)(bnt + toff);
            float bnv[8];
            bnv[0] = bf2f(bp.x & 0xFFFF); bnv[1] = bf2f(bp.x >> 16);
            bnv[2] = bf2f(bp.y & 0xFFFF); bnv[3] = bf2f(bp.y >> 16);
            bnv[4] = bf2f(bp.z & 0xFFFF); bnv[5] = bf2f(bp.z >> 16);
            bnv[6] = bf2f(bp.w & 0xFFFF); bnv[7] = bf2f(bp.w >> 16);
#pragma unroll
            for (int h = 0; h < HH; h++) {
                const uint4 ap = *(const uint4*)(ant + (size_t)h * 1048576 + toff);
                float av[8];
                av[0] = bf2f(ap.x & 0xFFFF); av[1] = bf2f(ap.x >> 16);
                av[2] = bf2f(ap.y & 0xFFFF); av[3] = bf2f(ap.y >> 16);
                av[4] = bf2f(ap.z & 0xFFFF); av[5] = bf2f(ap.z >> 16);
                av[6] = bf2f(ap.w & 0xFFFF); av[7] = bf2f(ap.w >> 16);
                unsigned short ow[8];
#pragma unroll
                for (int r = 0; r < 8; r++) ow[r] = f2bf(ibs * bnv[r] + ias[h] * av[r]);
                uint4 pk;
                pk.x = ow[0] | ((unsigned)ow[1] << 16);
                pk.y = ow[2] | ((unsigned)ow[3] << 16);
                pk.z = ow[4] | ((unsigned)ow[5] << 16);
                pk.w = ow[6] | ((unsigned)ow[7] << 16);
                *(uint4*)(At + (size_t)h * 1048576 + toff) = pk;
            }
        }
    }
}

// ================================================================ Clenshaw GEMM (R10: LDS-staged, counted-vmcnt pipeline)
// R9 result: direct-global fragments = 268 MB/launch L2-side traffic at
// 16 FLOP/B; per-XCD working set (A 2MB + B 1MB + streamed P/Q 2MB) > 4MB L2
// -> A/B re-reads spill to Infinity Cache. R10: (1) quad-buffered LDS staging
// via global_load_lds (each block reads its panels ONCE: 134 MB/launch),
// prefetch 3 K-steps ahead, vmcnt counted 6/4/2/0 (never drained mid-loop),
// raw s_barrier pairs; (2) nontemporal P/Q epilogue loads so the streams do
// not evict the A/B hot set. Accumulation order per element is unchanged.
__global__ __launch_bounds__(256) void gemm_mf(
    const short* __restrict__ At, const short* __restrict__ Bt,
    const short* __restrict__ Pt, const short* __restrict__ Qt,
    short* __restrict__ Ot, float scale, float pc, float qc)
{
    const int bid = blockIdx.x;                        // 512 blocks, 1D
    const int h = (bid & 7) >> 1;                      // XCD-pair affinity
    const int tile = ((bid >> 3) << 1) | (bid & 1);    // 0..127
    const int c0 = (tile & 7) * 64;
    const int r0 = (tile >> 3) * 64;

    const short* Ah = At + (size_t)h * 1048576;
    const short* Bh = Bt + (size_t)h * 524288;
    const short* Ph = Pt + (size_t)h * 524288;
    const short* Qh = Qt + (size_t)h * 524288;
    short* Oh = Ot + (size_t)h * 524288;

    const int tid = threadIdx.x;
    const int wave = tid >> 6, lane = tid & 63;
    const int q = lane >> 4, m16 = lane & 15;
    const int wr = wave >> 1, wc = wave & 1;

    // LDS: [buf 4][kc 4][row/col 64][8 shorts] per operand = 16 KB each
    __shared__ __align__(16) short Asm[4][4][64][8];
    __shared__ __align__(16) short Bsm[4][4][64][8];

    const char* Abase = (const char*)Ah + (size_t)r0 * 16;  // + kc*16384 + row*16
    const char* Bbase = (const char*)Bh + (size_t)c0 * 16;  // + kc*8192  + col*16

    // wave w stages kc-chunk (it*4+w): 1 KB of A + 1 KB of B (2 vmcnt events)
#define STAGE_MF(itc, bufc)                                                     \
    do {                                                                        \
        const size_t ko_ = (size_t)((itc) * 4 + wave);                          \
        GLD16(Abase + ko_ * 16384 + (size_t)lane * 16, &Asm[bufc][wave][0][0]); \
        GLD16(Bbase + ko_ * 8192  + (size_t)lane * 16, &Bsm[bufc][wave][0][0]); \
    } while (0)

    f32x4 acc[2][2];
#pragma unroll
    for (int mi = 0; mi < 2; mi++)
#pragma unroll
        for (int ni = 0; ni < 2; ni++) acc[mi][ni] = (f32x4){0.f, 0.f, 0.f, 0.f};

    STAGE_MF(0, 0);
    STAGE_MF(1, 1);
    STAGE_MF(2, 2);

#pragma unroll
    for (int it = 0; it < 32; ++it) {
        if (it < 29) STAGE_MF(it + 3, (it + 3) & 3);
        if (it < 29)      asm volatile("s_waitcnt vmcnt(6)" ::: "memory");
        else if (it == 29) asm volatile("s_waitcnt vmcnt(4)" ::: "memory");
        else if (it == 30) asm volatile("s_waitcnt vmcnt(2)" ::: "memory");
        else               asm volatile("s_waitcnt vmcnt(0)" ::: "memory");
        __builtin_amdgcn_s_barrier();

        const int b = it & 3;
        const bf16x8 af0 = *(const bf16x8*)&Asm[b][q][wr * 32 + m16][0];
        const bf16x8 af1 = *(const bf16x8*)&Asm[b][q][wr * 32 + 16 + m16][0];
        const bf16x8 bf0 = *(const bf16x8*)&Bsm[b][q][wc * 32 + m16][0];
        const bf16x8 bf1 = *(const bf16x8*)&Bsm[b][q][wc * 32 + 16 + m16][0];
        acc[0][0] = __builtin_amdgcn_mfma_f32_16x16x32_bf16(af0, bf0, acc[0][0], 0, 0, 0);
        acc[0][1] = __builtin_amdgcn_mfma_f32_16x16x32_bf16(af0, bf1, acc[0][1], 0, 0, 0);
        acc[1][0] = __builtin_amdgcn_mfma_f32_16x16x32_bf16(af1, bf0, acc[1][0], 0, 0, 0);
        acc[1][1] = __builtin_amdgcn_mfma_f32_16x16x32_bf16(af1, bf1, acc[1][1], 0, 0, 0);

        __builtin_amdgcn_s_barrier();
    }
#undef STAGE_MF

#pragma unroll
    for (int mi = 0; mi < 2; mi++) {
        const int row0 = r0 + wr * 32 + mi * 16 + q * 4;
#pragma unroll
        for (int ni = 0; ni < 2; ni++) {
            const int cc = c0 + wc * 32 + ni * 16 + m16;
            const size_t off = ((size_t)(row0 >> 3) * 512 + cc) * 8 + (row0 & 7);
            const u16x4 pv = __builtin_nontemporal_load((const u16x4*)(Ph + off));
            float v[4];
            v[0] = scale * acc[mi][ni][0] + pc * bf2f(pv[0]);
            v[1] = scale * acc[mi][ni][1] + pc * bf2f(pv[1]);
            v[2] = scale * acc[mi][ni][2] + pc * bf2f(pv[2]);
            v[3] = scale * acc[mi][ni][3] + pc * bf2f(pv[3]);
            if (qc != 0.f) {
                const u16x4 qv = __builtin_nontemporal_load((const u16x4*)(Qh + off));
                v[0] += qc * bf2f(qv[0]); v[1] += qc * bf2f(qv[1]);
                v[2] += qc * bf2f(qv[2]); v[3] += qc * bf2f(qv[3]);
            }
            ushort4 pk;
            pk.x = f2bf(v[0]); pk.y = f2bf(v[1]); pk.z = f2bf(v[2]); pk.w = f2bf(v[3]);
            // O stays L2-cached: next launch's B-operand reads it on the SAME XCD.
            *(ushort4*)(Oh + off) = pk;
        }
    }
}

// ================================================================ GEMM3 + fused output contraction
// Same LDS-staged pipeline; epilogue contracts with psi_emb/f_b, shfl-reduces
// over the 16 d-lanes, atomicAdds mw[h]*sum into out (zeroed by phase1).
__global__ __launch_bounds__(256) void gemm3_out(
    const short* __restrict__ At, const short* __restrict__ Bt,
    const short* __restrict__ Pt, const short* __restrict__ Qt,
    const float* __restrict__ psi_emb, const float* __restrict__ f_b,
    const float* __restrict__ head_mix, float* __restrict__ out)
{
    const int bid = blockIdx.x;                        // 512 blocks, 1D
    const int h = (bid & 7) >> 1;
    const int tile = ((bid >> 3) << 1) | (bid & 1);
    const int c0 = (tile & 7) * 64;
    const int r0 = (tile >> 3) * 64;

    const short* Ah = At + (size_t)h * 1048576;
    const short* Bh = Bt + (size_t)h * 524288;
    const short* Ph = Pt + (size_t)h * 524288;
    const short* Qh = Qt + (size_t)h * 524288;

    const int tid = threadIdx.x;
    const int wave = tid >> 6, lane = tid & 63;
    const int q = lane >> 4, m16 = lane & 15;
    const int wr = wave >> 1, wc = wave & 1;

    __shared__ float es[64][17];
    __shared__ __align__(16) short Asm[4][4][64][8];
    __shared__ __align__(16) short Bsm[4][4][64][8];

    {
        const int row = tid >> 2, dq = (tid & 3) * 4;
        const float4 ev = *(const float4*)(psi_emb + (size_t)(r0 + row) * DE + dq);
        es[row][dq] = ev.x; es[row][dq + 1] = ev.y;
        es[row][dq + 2] = ev.z; es[row][dq + 3] = ev.w;
    }
    __syncthreads();   // drains vmcnt to 0 -> clean slate for counted waits

    const char* Abase = (const char*)Ah + (size_t)r0 * 16;
    const char* Bbase = (const char*)Bh + (size_t)c0 * 16;

#define STAGE_G3(itc, bufc)                                                     \
    do {                                                                        \
        const size_t ko_ = (size_t)((itc) * 4 + wave);                          \
        GLD16(Abase + ko_ * 16384 + (size_t)lane * 16, &Asm[bufc][wave][0][0]); \
        GLD16(Bbase + ko_ * 8192  + (size_t)lane * 16, &Bsm[bufc][wave][0][0]); \
    } while (0)

    f32x4 acc[2][2];
#pragma unroll
    for (int mi = 0; mi < 2; mi++)
#pragma unroll
        for (int ni = 0; ni < 2; ni++) acc[mi][ni] = (f32x4){0.f, 0.f, 0.f, 0.f};

    STAGE_G3(0, 0);
    STAGE_G3(1, 1);
    STAGE_G3(2, 2);

#pragma unroll
    for (int it = 0; it < 32; ++it) {
        if (it < 29) STAGE_G3(it + 3, (it + 3) & 3);
        if (it < 29)      asm volatile("s_waitcnt vmcnt(6)" ::: "memory");
        else if (it == 29) asm volatile("s_waitcnt vmcnt(4)" ::: "memory");
        else if (it == 30) asm volatile("s_waitcnt vmcnt(2)" ::: "memory");
        else               asm volatile("s_waitcnt vmcnt(0)" ::: "memory");
        __builtin_amdgcn_s_barrier();

        const int b = it & 3;
        const bf16x8 af0 = *(const bf16x8*)&Asm[b][q][wr * 32 + m16][0];
        const bf16x8 af1 = *(const bf16x8*)&Asm[b][q][wr * 32 + 16 + m16][0];
        const bf16x8 bf0 = *(const bf16x8*)&Bsm[b][q][wc * 32 + m16][0];
        const bf16x8 bf1 = *(const bf16x8*)&Bsm[b][q][wc * 32 + 16 + m16][0];
        acc[0][0] = __builtin_amdgcn_mfma_f32_16x16x32_bf16(af0, bf0, acc[0][0], 0, 0, 0);
        acc[0][1] = __builtin_amdgcn_mfma_f32_16x16x32_bf16(af0, bf1, acc[0][1], 0, 0, 0);
        acc[1][0] = __builtin_amdgcn_mfma_f32_16x16x32_bf16(af1, bf0, acc[1][0], 0, 0, 0);
        acc[1][1] = __builtin_amdgcn_mfma_f32_16x16x32_bf16(af1, bf1, acc[1][1], 0, 0, 0);

        __builtin_amdgcn_s_barrier();
    }
#undef STAGE_G3

    const float hm0 = head_mix[0], hm1 = head_mix[1], hm2 = head_mix[2], hm3 = head_mix[3];
    const float mx = fmaxf(fmaxf(hm0, hm1), fmaxf(hm2, hm3));
    const float w0 = expf(hm0 - mx), w1 = expf(hm1 - mx), w2 = expf(hm2 - mx), w3 = expf(hm3 - mx);
    const float isum = 1.f / (w0 + w1 + w2 + w3);
    const float mwh = (h == 0 ? w0 : h == 1 ? w1 : h == 2 ? w2 : w3) * isum;
    const float fb = f_b[h * DE + m16];

#pragma unroll
    for (int mi = 0; mi < 2; mi++) {
        const int rloc0 = wr * 32 + mi * 16 + q * 4;
        const int row0 = r0 + rloc0;
#pragma unroll
        for (int ni = 0; ni < 2; ni++) {
            const int cc = c0 + wc * 32 + ni * 16 + m16;
            const int b = cc >> 4;
            const size_t off = ((size_t)(row0 >> 3) * 512 + cc) * 8 + (row0 & 7);
            const u16x4 pv = __builtin_nontemporal_load((const u16x4*)(Ph + off));
            const u16x4 qv = __builtin_nontemporal_load((const u16x4*)(Qh + off));
            float v[4];
            v[0] = acc[mi][ni][0] + bf2f(pv[0]) - bf2f(qv[0]);
            v[1] = acc[mi][ni][1] + bf2f(pv[1]) - bf2f(qv[1]);
            v[2] = acc[mi][ni][2] + bf2f(pv[2]) - bf2f(qv[2]);
            v[3] = acc[mi][ni][3] + bf2f(pv[3]) - bf2f(qv[3]);
#pragma unroll
            for (int r = 0; r < 4; r++) {
                float w = es[rloc0 + r][m16] * (v[r] + fb);
                w += __shfl_xor(w, 1, 64);
                w += __shfl_xor(w, 2, 64);
                w += __shfl_xor(w, 4, 64);
                w += __shfl_xor(w, 8, 64);
                if (m16 == 0)
                    atomicAdd(out + (size_t)b * NN + (row0 + r), mwh * w);
            }
        }
    }
}

extern "C" void kernel_launch(void* const* d_in, const int* in_sizes, int n_in,
                              void* d_out, int out_size, void* d_ws, size_t ws_size,
                              hipStream_t stream)
{
    const float* x          = (const float*)d_in[0];
    const float* psi_emb    = (const float*)d_in[1];
    const float* psi        = (const float*)d_in[2];
    const float* W_q        = (const float*)d_in[3];
    const float* W_k        = (const float*)d_in[4];
    const float* attn_alpha = (const float*)d_in[5];
    const float* F_w        = (const float*)d_in[6];
    const float* f_b        = (const float*)d_in[7];
    const float* head_mix   = (const float*)d_in[8];
    float* out = (float*)d_out;

    short* At  = (short*)d_ws;                 // 4,194,304 shorts (per-h 1,048,576)
    short* xt  = At + 4194304;                 // 4,194,304
    short* wtt = xt + 4194304;                 // 32,768
    short* Gt  = wtt + 32768;                  // 16 slabs (k*4+h) x 524,288 shorts
    short* b2t = Gt + 8388608;                 // 2,097,152
    short* b1t = b2t + 2097152;                // 2,097,152
    short* bnt = b1t + 2097152;                // 1,048,576
    short* ant = bnt + 1048576;                // 4,194,304
    float* partials = (float*)(ant + 4194304); // 81,920 fp32

    const size_t need_bytes =
        (size_t)(4194304 + 4194304 + 32768 + 8388608 + 2097152 + 2097152 + 1048576 + 4194304) * 2 +
        (size_t)81920 * 4;
    if (ws_size < need_bytes) return;

    phase1<<<800, 256, 0, stream>>>(psi_emb, psi, W_q, W_k, x, F_w,
                                    bnt, ant, partials, xt, wtt, out);
    phase2<<<1280, 256, 0, stream>>>(xt, wtt, Gt, bnt, ant, partials,
                                     attn_alpha, At);

    // b2t = bf16(G2 + 2*A@G3)
    gemm_mf<<<512, 256, 0, stream>>>(At, Gt + 12 * (size_t)524288, Gt + 8 * (size_t)524288,
                                     Gt /*unused*/, b2t, 2.f, 1.f, 0.f);
    // b1t = bf16(G1 + 2*A@b2 - G3)
    gemm_mf<<<512, 256, 0, stream>>>(At, b2t, Gt + 4 * (size_t)524288,
                                     Gt + 12 * (size_t)524288, b1t, 2.f, 1.f, -1.f);
    // out += mw[h] * e·(G0 + A@b1 - b2 + fb)
    gemm3_out<<<512, 256, 0, stream>>>(At, b1t, Gt, b2t, psi_emb, f_b, head_mix, out);
}

// Round 2
// 149.835 us; speedup vs baseline: 1.0045x; 1.0045x over previous
//
#include <hip/hip_runtime.h>
#include <cstdint>

#define NN 1024
#define BB 32
#define LL 128
#define DE 16
#define HH 4
#define K1 4
#define BD 512
#define NS 524288   // NN*BD elements per head slab

using bf16x8 = __attribute__((ext_vector_type(8))) short;
using f32x4  = __attribute__((ext_vector_type(4))) float;
using u16x4  = __attribute__((ext_vector_type(4))) unsigned short;

__device__ inline unsigned short f2bf(float f) {
    unsigned u = __builtin_bit_cast(unsigned, f);
    u += 0x7FFFu + ((u >> 16) & 1u);          // round-to-nearest-even
    return (unsigned short)(u >> 16);
}
__device__ inline float bf2f(unsigned short u) {
    return __builtin_bit_cast(float, (unsigned)u << 16);
}
__device__ inline ushort4 pk4(unsigned short a, unsigned short b,
                              unsigned short c, unsigned short d) {
    ushort4 t; t.x = a; t.y = b; t.z = c; t.w = d; return t;
}

// async global->LDS, 16B per lane; LDS dest is wave-uniform base + lane*16
typedef const __attribute__((address_space(1))) void gas_void;
typedef __attribute__((address_space(3))) void las_void;
#define GLD16(gsrc, ldst) \
    __builtin_amdgcn_global_load_lds((gas_void*)(gsrc), (las_void*)(ldst), 16, 0, 0)

// R11 logits smem: MFMA operand tiles in bf16 hi/lo split form.
// Strides chosen for 16B alignment + >=8 bank-group spread on b128 reads:
//   E rows: 56 shorts (112B = 28 words -> m16*28%32 cycles 8 groups)
//   QK rows: 136 shorts (272B = 68 words -> m16*68%32 = m16*4 -> 8 groups)
struct LogitsSmem {
    float wqs[1024];          // W_q flat [d][h][m]
    float wks[1024];
    short EAj[64][56];        // row j: [0..15]=hi, [16..31]=lo, rest pad
    short EBi[64][56];        // row i: same
    short KAj[64][136];       // row j, head h at [h*32 .. ]: hi|lo
    short QBi[64][136];       // row i, head h at [h*32 .. ]: hi|lo
    float nis[64];
    float njs[64];
    float part[4][5][64];
    short zblk[8];            // 16B of zeros for pass-2 B upper-K
};
struct XtSmem { float xs[64][128]; };

// ================================================================ PHASE 1
// logits (256) | xt_cast (512) | wtt_cast (16) | zero-out (16) = 800 blocks.
// R11: logits role rewritten on MFMA. dist2 = ni + nj - 2*ei.ej and Q.K are
// K=16 GEMMs; scalar LDS-operand FMAs (~1800 ds_read/thread, ~35us of LDS
// issue per CU) replaced by 40 MFMA/wave with hi/lo bf16 split (2-pass K=32:
// P1 A[hi|lo]*B[hi|hi], P2 A[hi|lo]*B[lo|0] => hihi+lohi+hilo, err ~2^-18).
__global__ __launch_bounds__(256) void phase1(
    const float* __restrict__ psi_emb, const float* __restrict__ psi_p,
    const float* __restrict__ W_q, const float* __restrict__ W_k,
    const float* __restrict__ x, const float* __restrict__ F_w,
    short* __restrict__ bnt, short* __restrict__ ant, float* __restrict__ partials,
    short* __restrict__ xt, short* __restrict__ wtt, float* __restrict__ out)
{
    __shared__ __align__(16) char smem_raw[sizeof(LogitsSmem)];
    const int bid = blockIdx.x;
    const int tid = threadIdx.x;

    if (bid < 256) {
        LogitsSmem& S = *(LogitsSmem*)smem_raw;
        const int jb = bid & 15, ib = bid >> 4;
        const int i0 = ib * 64, j0 = jb * 64;

        // ---- region 0: stage W, zero block
        *(float4*)&S.wqs[tid * 4] = *(const float4*)(W_q + tid * 4);
        *(float4*)&S.wks[tid * 4] = *(const float4*)(W_k + tid * 4);
        if (tid == 0) {
            const bf16x8 z = {0, 0, 0, 0, 0, 0, 0, 0};
            *(bf16x8*)&S.zblk[0] = z;
        }
        __syncthreads();

        // ---- region 1: Q/K projection (fp32, d-ascending: bit-identical to
        // old path) + hi/lo splits + norms. thread = (row 0..63, h 0..3).
        {
            const int prow = tid >> 2, ph = tid & 3;
            float ei[DE], ej[DE];
            {
                const float* pei = psi_emb + (size_t)(i0 + prow) * DE;
                const float* pej = psi_emb + (size_t)(j0 + prow) * DE;
#pragma unroll
                for (int c = 0; c < 4; c++) {
                    const float4 vi = *(const float4*)(pei + c * 4);
                    ei[c * 4] = vi.x; ei[c * 4 + 1] = vi.y;
                    ei[c * 4 + 2] = vi.z; ei[c * 4 + 3] = vi.w;
                    const float4 vj = *(const float4*)(pej + c * 4);
                    ej[c * 4] = vj.x; ej[c * 4 + 1] = vj.y;
                    ej[c * 4 + 2] = vj.z; ej[c * 4 + 3] = vj.w;
                }
            }
            float qv[16], kv[16];
#pragma unroll
            for (int m = 0; m < 16; m++) { qv[m] = 0.f; kv[m] = 0.f; }
#pragma unroll
            for (int d = 0; d < DE; d++) {
                const float eid = ei[d], ejd = ej[d];
#pragma unroll
                for (int m = 0; m < 16; m++) {
                    qv[m] += eid * S.wqs[d * 64 + ph * 16 + m];
                    kv[m] += ejd * S.wks[d * 64 + ph * 16 + m];
                }
            }
            unsigned short qh[16], ql[16], kh[16], kl[16];
#pragma unroll
            for (int m = 0; m < 16; m++) {
                qh[m] = f2bf(qv[m]); ql[m] = f2bf(qv[m] - bf2f(qh[m]));
                kh[m] = f2bf(kv[m]); kl[m] = f2bf(kv[m] - bf2f(kh[m]));
            }
#pragma unroll
            for (int c = 0; c < 4; c++) {
                *(ushort4*)&S.QBi[prow][ph * 32 + c * 4] =
                    pk4(qh[c * 4], qh[c * 4 + 1], qh[c * 4 + 2], qh[c * 4 + 3]);
                *(ushort4*)&S.QBi[prow][ph * 32 + 16 + c * 4] =
                    pk4(ql[c * 4], ql[c * 4 + 1], ql[c * 4 + 2], ql[c * 4 + 3]);
                *(ushort4*)&S.KAj[prow][ph * 32 + c * 4] =
                    pk4(kh[c * 4], kh[c * 4 + 1], kh[c * 4 + 2], kh[c * 4 + 3]);
                *(ushort4*)&S.KAj[prow][ph * 32 + 16 + c * 4] =
                    pk4(kl[c * 4], kl[c * 4 + 1], kl[c * 4 + 2], kl[c * 4 + 3]);
            }
            if (ph == 0) {
                float ni = 0.f, nj = 0.f;
#pragma unroll
                for (int d = 0; d < DE; d++) { ni += ei[d] * ei[d]; nj += ej[d] * ej[d]; }
                S.nis[prow] = ni; S.njs[prow] = nj;
                unsigned short ih[16], il[16], jh[16], jl[16];
#pragma unroll
                for (int d = 0; d < DE; d++) {
                    ih[d] = f2bf(ei[d]); il[d] = f2bf(ei[d] - bf2f(ih[d]));
                    jh[d] = f2bf(ej[d]); jl[d] = f2bf(ej[d] - bf2f(jh[d]));
                }
#pragma unroll
                for (int c = 0; c < 4; c++) {
                    *(ushort4*)&S.EBi[prow][c * 4] =
                        pk4(ih[c * 4], ih[c * 4 + 1], ih[c * 4 + 2], ih[c * 4 + 3]);
                    *(ushort4*)&S.EBi[prow][16 + c * 4] =
                        pk4(il[c * 4], il[c * 4 + 1], il[c * 4 + 2], il[c * 4 + 3]);
                    *(ushort4*)&S.EAj[prow][c * 4] =
                        pk4(jh[c * 4], jh[c * 4 + 1], jh[c * 4 + 2], jh[c * 4 + 3]);
                    *(ushort4*)&S.EAj[prow][16 + c * 4] =
                        pk4(jl[c * 4], jl[c * 4 + 1], jl[c * 4 + 2], jl[c * 4 + 3]);
                }
            }
        }
        __syncthreads();

        // ---- region 2: MFMA dots + epilogues.
        // Wave w owns j-strip [w*16, w*16+16). A-frag row = m16 (j side),
        // C row = q*4+r (j), C col = m16 (i) -- layouts verified by gemm_mf.
        const int w = tid >> 6, lane = tid & 63;
        const int q = lane >> 4, m16 = lane & 15;
        const float psi = psi_p[0];
        const short* zb = &S.zblk[0];

        // ---------- bnorm
        {
            const bf16x8 aB = *(const bf16x8*)&S.EAj[w * 16 + m16][q * 8];
            f32x4 acc[4];
#pragma unroll
            for (int ct = 0; ct < 4; ct++) acc[ct] = (f32x4){0.f, 0.f, 0.f, 0.f};
#pragma unroll
            for (int ct = 0; ct < 4; ct++) {
                const short* bc = &S.EBi[ct * 16 + m16][0];
                const bf16x8 b1 = *(const bf16x8*)(bc + (q & 1) * 8);
                const bf16x8 b2 = *(const bf16x8*)(q < 2 ? bc + 16 + q * 8 : zb);
                acc[ct] = __builtin_amdgcn_mfma_f32_16x16x32_bf16(aB, b1, acc[ct], 0, 0, 0);
                acc[ct] = __builtin_amdgcn_mfma_f32_16x16x32_bf16(aB, b2, acc[ct], 0, 0, 0);
            }
            float njr[4];
#pragma unroll
            for (int r = 0; r < 4; r++) njr[r] = S.njs[w * 16 + q * 4 + r];
            const size_t tbase = (size_t)((j0 + w * 16 + q * 4) >> 3) * 8192 + (q & 1) * 4;
#pragma unroll
            for (int ct = 0; ct < 4; ct++) {
                const float nii = S.nis[ct * 16 + m16];
                float s = 0.f; unsigned short pw[4];
#pragma unroll
                for (int r = 0; r < 4; r++) {
                    const float d2 = nii + njr[r] - 2.f * acc[ct][r];
                    const float bn = __expf(__expf(-psi * d2));
                    s += bn; pw[r] = f2bf(bn);
                }
                *(ushort4*)(bnt + tbase + (size_t)(i0 + ct * 16 + m16) * 8) =
                    pk4(pw[0], pw[1], pw[2], pw[3]);
                s += __shfl_xor(s, 16, 64);
                s += __shfl_xor(s, 32, 64);
                if (q == 0) S.part[w][0][ct * 16 + m16] = s;
            }
        }
        // ---------- attention heads
#pragma unroll
        for (int h = 0; h < HH; h++) {
            const bf16x8 aK = *(const bf16x8*)&S.KAj[w * 16 + m16][h * 32 + q * 8];
            f32x4 acc[4];
#pragma unroll
            for (int ct = 0; ct < 4; ct++) acc[ct] = (f32x4){0.f, 0.f, 0.f, 0.f};
#pragma unroll
            for (int ct = 0; ct < 4; ct++) {
                const short* qc = &S.QBi[ct * 16 + m16][h * 32];
                const bf16x8 b1 = *(const bf16x8*)(qc + (q & 1) * 8);
                const bf16x8 b2 = *(const bf16x8*)(q < 2 ? qc + 16 + q * 8 : zb);
                acc[ct] = __builtin_amdgcn_mfma_f32_16x16x32_bf16(aK, b1, acc[ct], 0, 0, 0);
                acc[ct] = __builtin_amdgcn_mfma_f32_16x16x32_bf16(aK, b2, acc[ct], 0, 0, 0);
            }
            const size_t tbase = (size_t)((j0 + w * 16 + q * 4) >> 3) * 8192 + (q & 1) * 4;
#pragma unroll
            for (int ct = 0; ct < 4; ct++) {
                float s = 0.f; unsigned short pw[4];
#pragma unroll
                for (int r = 0; r < 4; r++) {
                    const float an = __expf(acc[ct][r] * 0.25f);
                    s += an; pw[r] = f2bf(an);
                }
                *(ushort4*)(ant + (size_t)h * 1048576 + tbase +
                            (size_t)(i0 + ct * 16 + m16) * 8) =
                    pk4(pw[0], pw[1], pw[2], pw[3]);
                s += __shfl_xor(s, 16, 64);
                s += __shfl_xor(s, 32, 64);
                if (q == 0) S.part[w][1 + h][ct * 16 + m16] = s;
            }
        }
        __syncthreads();
        if (tid < 64) {
#pragma unroll
            for (int s = 0; s < 5; s++) {
                const float v = S.part[0][s][tid] + S.part[1][s][tid] +
                                S.part[2][s][tid] + S.part[3][s][tid];
                partials[(size_t)jb * 5120 + (size_t)s * 1024 + i0 + tid] = v;
            }
        }
    } else if (bid < 768) {
        // ---------------- xt_cast role
        XtSmem& X = *(XtSmem*)smem_raw;
        const int idx = bid - 256;
        const int m0 = (idx & 15) * 64;
        const int b  = idx >> 4;
        for (int i = tid; i < 2048; i += 256) {
            const int row = i >> 5, lq = i & 31;
            *(float4*)&X.xs[row][lq * 4] =
                *(const float4*)(x + ((size_t)(b * NN + m0 + row)) * LL + lq * 4);
        }
        __syncthreads();
        for (int j = tid; j < 1024; j += 256) {
            const int m = j & 63, lc = j >> 6;
            const float* s = &X.xs[m][lc * 8];
            uint4 pk;
            pk.x = f2bf(s[0]) | ((unsigned)f2bf(s[1]) << 16);
            pk.y = f2bf(s[2]) | ((unsigned)f2bf(s[3]) << 16);
            pk.z = f2bf(s[4]) | ((unsigned)f2bf(s[5]) << 16);
            pk.w = f2bf(s[6]) | ((unsigned)f2bf(s[7]) << 16);
            *(uint4*)(xt + (size_t)b * 131072 + (size_t)lc * 8192 + (size_t)(m0 + m) * 8) = pk;
        }
    } else if (bid < 784) {
        // ---------------- wtt_cast role
        const int j = (bid - 768) * 256 + tid;
        const int lc = j >> 8, c = j & 255;
        const int h = c >> 6, k = (c >> 4) & 3, d = c & 15;
        const float* s = F_w + (size_t)((h * DE + d) * K1 + k) * LL + lc * 8;
        uint4 pk;
        pk.x = f2bf(s[0]) | ((unsigned)f2bf(s[1]) << 16);
        pk.y = f2bf(s[2]) | ((unsigned)f2bf(s[3]) << 16);
        pk.z = f2bf(s[4]) | ((unsigned)f2bf(s[5]) << 16);
        pk.w = f2bf(s[6]) | ((unsigned)f2bf(s[7]) << 16);
        *(uint4*)(wtt + (size_t)lc * 2048 + (size_t)c * 8) = pk;
    } else {
        // ---------------- zero-out role (out is poisoned 0xAA each launch)
        const int idx = (bid - 784) * 256 + tid;       // 4096 threads, 8 floats each
        const float4 z = {0.f, 0.f, 0.f, 0.f};
        *(float4*)(out + (size_t)idx * 8) = z;
        *(float4*)(out + (size_t)idx * 8 + 4) = z;
    }
}

// ================================================================ PHASE 2
// g_mfma (1024 blocks, all-bf16 tiled Gt output) + blend (256 blocks).
__global__ __launch_bounds__(256) void phase2(
    const short* __restrict__ xt, const short* __restrict__ wtt,
    short* __restrict__ Gt,
    const short* __restrict__ bnt, const short* __restrict__ ant,
    const float* __restrict__ partials, const float* __restrict__ alpha_p,
    short* __restrict__ At)
{
    const int bid = blockIdx.x;
    const int tid = threadIdx.x;
    __shared__ float sums_l[5][64];

    if (bid < 1024) {
        // ---------------- g_mfma role
        const int cb = bid & 3;
        const int m0 = ((bid >> 2) & 15) * 64;
        const int bp = bid >> 6;
        const int wave = tid >> 6, lane = tid & 63;
        const int b  = bp * 2 + (wave >> 1);
        const int wc = wave & 1;
        const int q = lane >> 4, m16 = lane & 15;
        const short* xb = xt + (size_t)b * 131072;

        f32x4 acc[4][2];
#pragma unroll
        for (int mi = 0; mi < 4; mi++)
#pragma unroll
            for (int ni = 0; ni < 2; ni++) acc[mi][ni] = (f32x4){0.f, 0.f, 0.f, 0.f};

#pragma unroll
        for (int ks = 0; ks < 4; ks++) {
            const int kc = ks * 4 + q;
            bf16x8 a[4], bb[2];
#pragma unroll
            for (int mi = 0; mi < 4; mi++)
                a[mi] = *(const bf16x8*)(xb + (size_t)kc * 8192 + (size_t)(m0 + mi * 16 + m16) * 8);
#pragma unroll
            for (int ni = 0; ni < 2; ni++)
                bb[ni] = *(const bf16x8*)(wtt + (size_t)kc * 2048 +
                                          (size_t)(cb * 64 + wc * 32 + ni * 16 + m16) * 8);
#pragma unroll
            for (int mi = 0; mi < 4; mi++)
#pragma unroll
                for (int ni = 0; ni < 2; ni++)
                    acc[mi][ni] = __builtin_amdgcn_mfma_f32_16x16x32_bf16(a[mi], bb[ni], acc[mi][ni], 0, 0, 0);
        }

        // bf16 tiled stores only (full-line coalesced); slab = kk*4+hh
#pragma unroll
        for (int ni = 0; ni < 2; ni++) {
            const int cc = cb * 64 + wc * 32 + ni * 16 + m16;
            const int kk = (cc >> 4) & 3, hh = cc >> 6;
            const int col512 = b * 16 + (cc & 15);
            short* gdst = Gt + (size_t)(kk * 4 + hh) * 524288;
#pragma unroll
            for (int mi = 0; mi < 4; mi++) {
                const int row0 = m0 + mi * 16 + q * 4;
                ushort4 pk;
                pk.x = f2bf(acc[mi][ni][0]); pk.y = f2bf(acc[mi][ni][1]);
                pk.z = f2bf(acc[mi][ni][2]); pk.w = f2bf(acc[mi][ni][3]);
                *(ushort4*)(gdst + ((size_t)(row0 >> 3) * 512 + col512) * 8 + (row0 & 7)) = pk;
            }
        }
    } else {
        // ---------------- blend role
        const int idx = bid - 1024;
        const int jb = idx & 15, ib = idx >> 4;
        const int i0 = ib * 64, j0 = jb * 64;
        const int lane = tid & 63, w = tid >> 6;
        {
            float acc = 0.f;
#pragma unroll
            for (int jb2 = 0; jb2 < 16; jb2++)
                acc += partials[(size_t)jb2 * 5120 + (size_t)w * 1024 + i0 + lane];
            sums_l[w][lane] = acc;
            if (w == 0) {
                float a4 = 0.f;
#pragma unroll
                for (int jb2 = 0; jb2 < 16; jb2++)
                    a4 += partials[(size_t)jb2 * 5120 + 4 * 1024 + i0 + lane];
                sums_l[4][lane] = a4;
            }
        }
        __syncthreads();
        const int i = lane, jg = w;
        const float alpha = 1.f / (1.f + __expf(-alpha_p[0]));
        const float ibs = alpha / sums_l[0][i];
        float ias[HH];
#pragma unroll
        for (int h = 0; h < HH; h++) ias[h] = (1.f - alpha) / sums_l[1 + h][i];

#pragma unroll
        for (int g = 0; g < 2; g++) {
            const size_t toff = (size_t)((j0 + jg * 16 + g * 8) >> 3) * 8192 + (size_t)(i0 + i) * 8;
            const uint4 bp = *(const uint4*)(bnt + toff);
            float bnv[8];
            bnv[0] = bf2f(bp.x & 0xFFFF); bnv[1] = bf2f(bp.x >> 16);
            bnv[2] = bf2f(bp.y & 0xFFFF); bnv[3] = bf2f(bp.y >> 16);
            bnv[4] = bf2f(bp.z & 0xFFFF); bnv[5] = bf2f(bp.z >> 16);
            bnv[6] = bf2f(bp.w & 0xFFFF); bnv[7] = bf2f(bp.w >> 16);
#pragma unroll
            for (int h = 0; h < HH; h++) {
                const uint4 ap = *(const uint4*)(ant + (size_t)h * 1048576 + toff);
                float av[8];
                av[0] = bf2f(ap.x & 0xFFFF); av[1] = bf2f(ap.x >> 16);
                av[2] = bf2f(ap.y & 0xFFFF); av[3] = bf2f(ap.y >> 16);
                av[4] = bf2f(ap.z & 0xFFFF); av[5] = bf2f(ap.z >> 16);
                av[6] = bf2f(ap.w & 0xFFFF); av[7] = bf2f(ap.w >> 16);
                unsigned short ow[8];
#pragma unroll
                for (int r = 0; r < 8; r++) ow[r] = f2bf(ibs * bnv[r] + ias[h] * av[r]);
                uint4 pk;
                pk.x = ow[0] | ((unsigned)ow[1] << 16);
                pk.y = ow[2] | ((unsigned)ow[3] << 16);
                pk.z = ow[4] | ((unsigned)ow[5] << 16);
                pk.w = ow[6] | ((unsigned)ow[7] << 16);
                *(uint4*)(At + (size_t)h * 1048576 + toff) = pk;
            }
        }
    }
}

// ================================================================ Clenshaw GEMM (LDS-staged, counted-vmcnt pipeline)
__global__ __launch_bounds__(256) void gemm_mf(
    const short* __restrict__ At, const short* __restrict__ Bt,
    const short* __restrict__ Pt, const short* __restrict__ Qt,
    short* __restrict__ Ot, float scale, float pc, float qc)
{
    const int bid = blockIdx.x;                        // 512 blocks, 1D
    const int h = (bid & 7) >> 1;                      // XCD-pair affinity
    const int tile = ((bid >> 3) << 1) | (bid & 1);    // 0..127
    const int c0 = (tile & 7) * 64;
    const int r0 = (tile >> 3) * 64;

    const short* Ah = At + (size_t)h * 1048576;
    const short* Bh = Bt + (size_t)h * 524288;
    const short* Ph = Pt + (size_t)h * 524288;
    const short* Qh = Qt + (size_t)h * 524288;
    short* Oh = Ot + (size_t)h * 524288;

    const int tid = threadIdx.x;
    const int wave = tid >> 6, lane = tid & 63;
    const int q = lane >> 4, m16 = lane & 15;
    const int wr = wave >> 1, wc = wave & 1;

    __shared__ __align__(16) short Asm[4][4][64][8];
    __shared__ __align__(16) short Bsm[4][4][64][8];

    const char* Abase = (const char*)Ah + (size_t)r0 * 16;  // + kc*16384 + row*16
    const char* Bbase = (const char*)Bh + (size_t)c0 * 16;  // + kc*8192  + col*16

#define STAGE_MF(itc, bufc)                                                     \
    do {                                                                        \
        const size_t ko_ = (size_t)((itc) * 4 + wave);                          \
        GLD16(Abase + ko_ * 16384 + (size_t)lane * 16, &Asm[bufc][wave][0][0]); \
        GLD16(Bbase + ko_ * 8192  + (size_t)lane * 16, &Bsm[bufc][wave][0][0]); \
    } while (0)

    f32x4 acc[2][2];
#pragma unroll
    for (int mi = 0; mi < 2; mi++)
#pragma unroll
        for (int ni = 0; ni < 2; ni++) acc[mi][ni] = (f32x4){0.f, 0.f, 0.f, 0.f};

    STAGE_MF(0, 0);
    STAGE_MF(1, 1);
    STAGE_MF(2, 2);

#pragma unroll
    for (int it = 0; it < 32; ++it) {
        if (it < 29) STAGE_MF(it + 3, (it + 3) & 3);
        if (it < 29)      asm volatile("s_waitcnt vmcnt(6)" ::: "memory");
        else if (it == 29) asm volatile("s_waitcnt vmcnt(4)" ::: "memory");
        else if (it == 30) asm volatile("s_waitcnt vmcnt(2)" ::: "memory");
        else               asm volatile("s_waitcnt vmcnt(0)" ::: "memory");
        __builtin_amdgcn_s_barrier();

        const int b = it & 3;
        const bf16x8 af0 = *(const bf16x8*)&Asm[b][q][wr * 32 + m16][0];
        const bf16x8 af1 = *(const bf16x8*)&Asm[b][q][wr * 32 + 16 + m16][0];
        const bf16x8 bf0 = *(const bf16x8*)&Bsm[b][q][wc * 32 + m16][0];
        const bf16x8 bf1 = *(const bf16x8*)&Bsm[b][q][wc * 32 + 16 + m16][0];
        acc[0][0] = __builtin_amdgcn_mfma_f32_16x16x32_bf16(af0, bf0, acc[0][0], 0, 0, 0);
        acc[0][1] = __builtin_amdgcn_mfma_f32_16x16x32_bf16(af0, bf1, acc[0][1], 0, 0, 0);
        acc[1][0] = __builtin_amdgcn_mfma_f32_16x16x32_bf16(af1, bf0, acc[1][0], 0, 0, 0);
        acc[1][1] = __builtin_amdgcn_mfma_f32_16x16x32_bf16(af1, bf1, acc[1][1], 0, 0, 0);

        __builtin_amdgcn_s_barrier();
    }
#undef STAGE_MF

#pragma unroll
    for (int mi = 0; mi < 2; mi++) {
        const int row0 = r0 + wr * 32 + mi * 16 + q * 4;
#pragma unroll
        for (int ni = 0; ni < 2; ni++) {
            const int cc = c0 + wc * 32 + ni * 16 + m16;
            const size_t off = ((size_t)(row0 >> 3) * 512 + cc) * 8 + (row0 & 7);
            const u16x4 pv = __builtin_nontemporal_load((const u16x4*)(Ph + off));
            float v[4];
            v[0] = scale * acc[mi][ni][0] + pc * bf2f(pv[0]);
            v[1] = scale * acc[mi][ni][1] + pc * bf2f(pv[1]);
            v[2] = scale * acc[mi][ni][2] + pc * bf2f(pv[2]);
            v[3] = scale * acc[mi][ni][3] + pc * bf2f(pv[3]);
            if (qc != 0.f) {
                const u16x4 qv = __builtin_nontemporal_load((const u16x4*)(Qh + off));
                v[0] += qc * bf2f(qv[0]); v[1] += qc * bf2f(qv[1]);
                v[2] += qc * bf2f(qv[2]); v[3] += qc * bf2f(qv[3]);
            }
            ushort4 pk;
            pk.x = f2bf(v[0]); pk.y = f2bf(v[1]); pk.z = f2bf(v[2]); pk.w = f2bf(v[3]);
            *(ushort4*)(Oh + off) = pk;
        }
    }
}

// ================================================================ GEMM3 + fused output contraction
__global__ __launch_bounds__(256) void gemm3_out(
    const short* __restrict__ At, const short* __restrict__ Bt,
    const short* __restrict__ Pt, const short* __restrict__ Qt,
    const float* __restrict__ psi_emb, const float* __restrict__ f_b,
    const float* __restrict__ head_mix, float* __restrict__ out)
{
    const int bid = blockIdx.x;                        // 512 blocks, 1D
    const int h = (bid & 7) >> 1;
    const int tile = ((bid >> 3) << 1) | (bid & 1);
    const int c0 = (tile & 7) * 64;
    const int r0 = (tile >> 3) * 64;

    const short* Ah = At + (size_t)h * 1048576;
    const short* Bh = Bt + (size_t)h * 524288;
    const short* Ph = Pt + (size_t)h * 524288;
    const short* Qh = Qt + (size_t)h * 524288;

    const int tid = threadIdx.x;
    const int wave = tid >> 6, lane = tid & 63;
    const int q = lane >> 4, m16 = lane & 15;
    const int wr = wave >> 1, wc = wave & 1;

    __shared__ float es[64][17];
    __shared__ __align__(16) short Asm[4][4][64][8];
    __shared__ __align__(16) short Bsm[4][4][64][8];

    {
        const int row = tid >> 2, dq = (tid & 3) * 4;
        const float4 ev = *(const float4*)(psi_emb + (size_t)(r0 + row) * DE + dq);
        es[row][dq] = ev.x; es[row][dq + 1] = ev.y;
        es[row][dq + 2] = ev.z; es[row][dq + 3] = ev.w;
    }
    __syncthreads();   // drains vmcnt to 0 -> clean slate for counted waits

    const char* Abase = (const char*)Ah + (size_t)r0 * 16;
    const char* Bbase = (const char*)Bh + (size_t)c0 * 16;

#define STAGE_G3(itc, bufc)                                                     \
    do {                                                                        \
        const size_t ko_ = (size_t)((itc) * 4 + wave);                          \
        GLD16(Abase + ko_ * 16384 + (size_t)lane * 16, &Asm[bufc][wave][0][0]); \
        GLD16(Bbase + ko_ * 8192  + (size_t)lane * 16, &Bsm[bufc][wave][0][0]); \
    } while (0)

    f32x4 acc[2][2];
#pragma unroll
    for (int mi = 0; mi < 2; mi++)
#pragma unroll
        for (int ni = 0; ni < 2; ni++) acc[mi][ni] = (f32x4){0.f, 0.f, 0.f, 0.f};

    STAGE_G3(0, 0);
    STAGE_G3(1, 1);
    STAGE_G3(2, 2);

#pragma unroll
    for (int it = 0; it < 32; ++it) {
        if (it < 29) STAGE_G3(it + 3, (it + 3) & 3);
        if (it < 29)      asm volatile("s_waitcnt vmcnt(6)" ::: "memory");
        else if (it == 29) asm volatile("s_waitcnt vmcnt(4)" ::: "memory");
        else if (it == 30) asm volatile("s_waitcnt vmcnt(2)" ::: "memory");
        else               asm volatile("s_waitcnt vmcnt(0)" ::: "memory");
        __builtin_amdgcn_s_barrier();

        const int b = it & 3;
        const bf16x8 af0 = *(const bf16x8*)&Asm[b][q][wr * 32 + m16][0];
        const bf16x8 af1 = *(const bf16x8*)&Asm[b][q][wr * 32 + 16 + m16][0];
        const bf16x8 bf0 = *(const bf16x8*)&Bsm[b][q][wc * 32 + m16][0];
        const bf16x8 bf1 = *(const bf16x8*)&Bsm[b][q][wc * 32 + 16 + m16][0];
        acc[0][0] = __builtin_amdgcn_mfma_f32_16x16x32_bf16(af0, bf0, acc[0][0], 0, 0, 0);
        acc[0][1] = __builtin_amdgcn_mfma_f32_16x16x32_bf16(af0, bf1, acc[0][1], 0, 0, 0);
        acc[1][0] = __builtin_amdgcn_mfma_f32_16x16x32_bf16(af1, bf0, acc[1][0], 0, 0, 0);
        acc[1][1] = __builtin_amdgcn_mfma_f32_16x16x32_bf16(af1, bf1, acc[1][1], 0, 0, 0);

        __builtin_amdgcn_s_barrier();
    }
#undef STAGE_G3

    const float hm0 = head_mix[0], hm1 = head_mix[1], hm2 = head_mix[2], hm3 = head_mix[3];
    const float mx = fmaxf(fmaxf(hm0, hm1), fmaxf(hm2, hm3));
    const float w0 = expf(hm0 - mx), w1 = expf(hm1 - mx), w2 = expf(hm2 - mx), w3 = expf(hm3 - mx);
    const float isum = 1.f / (w0 + w1 + w2 + w3);
    const float mwh = (h == 0 ? w0 : h == 1 ? w1 : h == 2 ? w2 : w3) * isum;
    const float fb = f_b[h * DE + m16];

#pragma unroll
    for (int mi = 0; mi < 2; mi++) {
        const int rloc0 = wr * 32 + mi * 16 + q * 4;
        const int row0 = r0 + rloc0;
#pragma unroll
        for (int ni = 0; ni < 2; ni++) {
            const int cc = c0 + wc * 32 + ni * 16 + m16;
            const int b = cc >> 4;
            const size_t off = ((size_t)(row0 >> 3) * 512 + cc) * 8 + (row0 & 7);
            const u16x4 pv = __builtin_nontemporal_load((const u16x4*)(Ph + off));
            const u16x4 qv = __builtin_nontemporal_load((const u16x4*)(Qh + off));
            float v[4];
            v[0] = acc[mi][ni][0] + bf2f(pv[0]) - bf2f(qv[0]);
            v[1] = acc[mi][ni][1] + bf2f(pv[1]) - bf2f(qv[1]);
            v[2] = acc[mi][ni][2] + bf2f(pv[2]) - bf2f(qv[2]);
            v[3] = acc[mi][ni][3] + bf2f(pv[3]) - bf2f(qv[3]);
#pragma unroll
            for (int r = 0; r < 4; r++) {
                float w = es[rloc0 + r][m16] * (v[r] + fb);
                w += __shfl_xor(w, 1, 64);
                w += __shfl_xor(w, 2, 64);
                w += __shfl_xor(w, 4, 64);
                w += __shfl_xor(w, 8, 64);
                if (m16 == 0)
                    atomicAdd(out + (size_t)b * NN + (row0 + r), mwh * w);
            }
        }
    }
}

extern "C" void kernel_launch(void* const* d_in, const int* in_sizes, int n_in,
                              void* d_out, int out_size, void* d_ws, size_t ws_size,
                              hipStream_t stream)
{
    const float* x          = (const float*)d_in[0];
    const float* psi_emb    = (const float*)d_in[1];
    const float* psi        = (const float*)d_in[2];
    const float* W_q        = (const float*)d_in[3];
    const float* W_k        = (const float*)d_in[4];
    const float* attn_alpha = (const float*)d_in[5];
    const float* F_w        = (const float*)d_in[6];
    const float* f_b        = (const float*)d_in[7];
    const float* head_mix   = (const float*)d_in[8];
    float* out = (float*)d_out;

    short* At  = (short*)d_ws;                 // 4,194,304 shorts (per-h 1,048,576)
    short* xt  = At + 4194304;                 // 4,194,304
    short* wtt = xt + 4194304;                 // 32,768
    short* Gt  = wtt + 32768;                  // 16 slabs (k*4+h) x 524,288 shorts
    short* b2t = Gt + 8388608;                 // 2,097,152
    short* b1t = b2t + 2097152;                // 2,097,152
    short* bnt = b1t + 2097152;                // 1,048,576
    short* ant = bnt + 1048576;                // 4,194,304
    float* partials = (float*)(ant + 4194304); // 81,920 fp32

    const size_t need_bytes =
        (size_t)(4194304 + 4194304 + 32768 + 8388608 + 2097152 + 2097152 + 1048576 + 4194304) * 2 +
        (size_t)81920 * 4;
    if (ws_size < need_bytes) return;

    phase1<<<800, 256, 0, stream>>>(psi_emb, psi, W_q, W_k, x, F_w,
                                    bnt, ant, partials, xt, wtt, out);
    phase2<<<1280, 256, 0, stream>>>(xt, wtt, Gt, bnt, ant, partials,
                                     attn_alpha, At);

    // b2t = bf16(G2 + 2*A@G3)
    gemm_mf<<<512, 256, 0, stream>>>(At, Gt + 12 * (size_t)524288, Gt + 8 * (size_t)524288,
                                     Gt /*unused*/, b2t, 2.f, 1.f, 0.f);
    // b1t = bf16(G1 + 2*A@b2 - G3)
    gemm_mf<<<512, 256, 0, stream>>>(At, b2t, Gt + 4 * (size_t)524288,
                                     Gt + 12 * (size_t)524288, b1t, 2.f, 1.f, -1.f);
    // out += mw[h] * e·(G0 + A@b1 - b2 + fb)
    gemm3_out<<<512, 256, 0, stream>>>(At, b1t, Gt, b2t, psi_emb, f_b, head_mix, out);
}